// Round 6
// baseline (396.504 us; speedup 1.0000x reference)
//
#include <hip/hip_runtime.h>
#include <stdint.h>

// attention_block: B=8, S=2048, H=1024, fp32 in/out, bf16 internal GEMMs.
// R10: occupancy play. R7/R8/R9 (all 1-block/CU 256x256 schedules) tied at
// ~370us -> the shared constraint is lockstep stage+vmcnt+barrier at 2
// waves/SIMD with no cross-block overlap. Rewrite GEMMs as 128x128 / 4-wave
// / 256-thread blocks sized for THREE blocks/CU (m97's proven TLP regime):
// acc 64 VGPR (64x64/wave), launch_bounds(256,3) (VGPR<=170), LDS = ring-3
// of 32-wide K-halves (48 KB). Counted vmcnt(4) (stage 2 halves ahead,
// never drain mid-loop), 1 barrier/phase, conflict-free chunk XOR, setprio,
// XCD grids. Grids: qr 1024, scores 2048, pv 1024 blocks (4-8/CU rounds).
// K-order per acc element unchanged -> bitwise-identical output.

#define DEVI __device__ __forceinline__

typedef __bf16 bf16x8 __attribute__((ext_vector_type(8)));
typedef float  f32x4  __attribute__((ext_vector_type(4)));

typedef __attribute__((address_space(3))) uint32_t lds_u32_t;
typedef __attribute__((address_space(1))) uint32_t glb_u32_t;

DEVI uint16_t f2bf(float f) {
  union { float f; uint32_t u; } v; v.f = f;
  uint32_t r = (v.u + 0x7fffu + ((v.u >> 16) & 1u)) >> 16;  // RNE
  return (uint16_t)r;
}
DEVI float bf2f(uint16_t b) {
  union { uint32_t u; float f; } v; v.u = ((uint32_t)b) << 16;
  return v.f;
}
DEVI float sigm(float x) { return 1.0f / (1.0f + __expf(-x)); }

DEVI void gl_lds16(const void* g, const void* lds_base) {
  __builtin_amdgcn_global_load_lds((glb_u32_t*)(uintptr_t)g,
                                   (lds_u32_t*)(uint32_t)(uintptr_t)lds_base,
                                   16, 0, 0);
}

// ================= 128x128 GEMM core, 4 waves, ring-3 ======================
// C[128x128] += A[128xK] * B[128xK]^T. 256 threads = 4 waves (2M x 2N),
// per-wave C 64x64 -> acc[4][4]. K consumed in 32-wide halves; LDS = ring-3
// of [128 rows][32 cols] slots (8 KB) per operand = 48 KB. Half h in slot
// h%3. Phase h: {read 8 frags from slot h%3; stage half h+2 (A+B, 4 ops);
// vmcnt(4) [waits half h+1, leaves h+2 in flight]; barrier; 16 MFMA}.
// WAR: stage(h+2) overwrites half h-1's slot, read before barrier(h-1) ->
// >=1 barrier separation (R7-proven). Chunk XOR ((row>>1)&3) on both the
// staging source and frag reads -> conflict-free b128 (R6-verified, 0 cnf).

#define SLOT128 (128 * 32)

DEVI void stage_half128(const uint16_t* __restrict__ src, size_t ld, int kbase,
                        uint16_t* slot, int tid) {
#pragma unroll
  for (int q = 0; q < 2; q++) {
    const int idx = q * 256 + tid;                     // 0..511 : 16B chunk id
    const int r = idx >> 2;                            // row 0..127
    const int cl = (((idx & 3) ^ ((r >> 1) & 3)) * 8); // swizzled source col
    gl_lds16(src + (size_t)r * ld + (kbase + cl),
             slot + (size_t)(q * 256 + (tid & ~63)) * 8);  // wave-uniform base
  }
}

DEVI void gemm128(const uint16_t* __restrict__ A, size_t lda,
                  const uint16_t* __restrict__ B, size_t ldb,
                  int K, uint16_t* sA, uint16_t* sB, f32x4 (&acc)[4][4])
{
  const int tid = threadIdx.x, lane = tid & 63, w = tid >> 6;
  const int wr = (w >> 1) * 64, wc = (w & 1) * 64;
  const int m16 = lane & 15, quad = lane >> 4;
  const int NH = K >> 5;
  const int sw = (quad ^ ((m16 >> 1) & 3)) * 8;       // conflict-free chunk

  // prologue: stage halves 0,1; wait half 0 (half 1 left in flight)
  stage_half128(B, ldb, 0, sB, tid);
  stage_half128(A, lda, 0, sA, tid);
  stage_half128(B, ldb, 32, sB + SLOT128, tid);
  stage_half128(A, lda, 32, sA + SLOT128, tid);
  asm volatile("s_waitcnt vmcnt(4)" ::: "memory");
  __builtin_amdgcn_s_barrier();

  int scur = 0;                                        // slot of half h
  for (int h = 0; h < NH; h++) {
    const uint16_t* a_s = sA + scur * SLOT128;
    const uint16_t* b_s = sB + scur * SLOT128;
    bf16x8 af[4], bv[4];
#pragma unroll
    for (int i = 0; i < 4; i++) {
      af[i] = *(const bf16x8*)(a_s + (wr + i * 16 + m16) * 32 + sw);
      bv[i] = *(const bf16x8*)(b_s + (wc + i * 16 + m16) * 32 + sw);
    }
    const int h2 = h + 2;
    if (h2 < NH) {
      int s2 = scur + 2; if (s2 >= 3) s2 -= 3;
      stage_half128(B, ldb, h2 * 32, sB + s2 * SLOT128, tid);
      stage_half128(A, lda, h2 * 32, sA + s2 * SLOT128, tid);
      asm volatile("s_waitcnt vmcnt(4)" ::: "memory"); // half h+1 resident
    } else {
      asm volatile("s_waitcnt vmcnt(0)" ::: "memory"); // tail drain
    }
    __builtin_amdgcn_s_barrier();
    __builtin_amdgcn_s_setprio(1);
#pragma unroll
    for (int mi = 0; mi < 4; mi++)
#pragma unroll
      for (int ni = 0; ni < 4; ni++)
        acc[mi][ni] = __builtin_amdgcn_mfma_f32_16x16x32_bf16(
            af[mi], bv[ni], acc[mi][ni], 0, 0, 0);
    __builtin_amdgcn_s_setprio(0);
    scur = (scur + 1 == 3) ? 0 : scur + 1;
  }
}

// ---------------- gate: gate2[j] = sig(.)·tanh(.) / sig(k'[j]) ------------
__global__ void gate_kernel(const float* __restrict__ v_prime,
                            const float* __restrict__ v1W, const float* __restrict__ v1b,
                            const float* __restrict__ v2W, const float* __restrict__ v2b,
                            const float* __restrict__ k_prime,
                            float* __restrict__ gate2)
{
  const int tid = threadIdx.x, lane = tid & 63, w = tid >> 6;
  const int j = blockIdx.x * 4 + w;
  float d1 = 0.f, d2 = 0.f;
  for (int it = 0; it < 16; it++) {
    int i = it * 64 + lane;
    float vp = sigm(v_prime[i]);
    d1 += vp * v1W[(size_t)j * 1024 + i];
    d2 += vp * v2W[(size_t)j * 1024 + i];
  }
  for (int off = 32; off; off >>= 1) { d1 += __shfl_xor(d1, off); d2 += __shfl_xor(d2, off); }
  if (lane == 0)
    gate2[j] = sigm(d1 + v1b[j]) * tanhf(d2 + v2b[j]) / sigm(k_prime[j]);
}

// ---------------- fp32 -> bf16 convert (qW) ----------------
__global__ void cvt_kernel(const float* __restrict__ src, uint16_t* __restrict__ dst)
{
  size_t i = ((size_t)blockIdx.x * 256 + threadIdx.x) * 4;
  float4 v = *(const float4*)(src + i);
  *(ushort4*)(dst + i) = make_ushort4(f2bf(v.x), f2bf(v.y), f2bf(v.z), f2bf(v.w));
}

// ---------------- LayerNorm: wave-per-row; xqn + kr only ------------------
__global__ __launch_bounds__(256) void ln_kernel(
    const float* __restrict__ x,
    const float* __restrict__ qn_w, const float* __restrict__ qn_b,
    const float* __restrict__ kvn_w, const float* __restrict__ kvn_b,
    const float* __restrict__ k_prime,
    uint16_t* __restrict__ xqn_bf, uint16_t* __restrict__ kr,
    float* __restrict__ krowsq)
{
  const int lane = threadIdx.x & 63, w = threadIdx.x >> 6;
  const int row = blockIdx.x * 4 + w;
  const float4* xr = (const float4*)(x + (size_t)row * 1024);
  float4 v[4];
  float s = 0.f, sq = 0.f;
#pragma unroll
  for (int i = 0; i < 4; i++) {
    v[i] = xr[i * 64 + lane];
    s  += v[i].x + v[i].y + v[i].z + v[i].w;
    sq += v[i].x * v[i].x + v[i].y * v[i].y + v[i].z * v[i].z + v[i].w * v[i].w;
  }
  for (int off = 32; off; off >>= 1) { s += __shfl_xor(s, off); sq += __shfl_xor(sq, off); }
  const float mean = s * (1.f / 1024.f);
  const float rstd = rsqrtf(sq * (1.f / 1024.f) - mean * mean + 1e-5f);

  float ksq = 0.f;
  const size_t o4 = (size_t)row * 256;
#pragma unroll
  for (int i = 0; i < 4; i++) {
    const int idx = i * 64 + lane;
    float4 qw = ((const float4*)qn_w)[idx],  qb4 = ((const float4*)qn_b)[idx];
    float4 kw = ((const float4*)kvn_w)[idx], kb4 = ((const float4*)kvn_b)[idx];
    float4 kp = ((const float4*)k_prime)[idx];
    float xn0 = (v[i].x - mean) * rstd, xn1 = (v[i].y - mean) * rstd;
    float xn2 = (v[i].z - mean) * rstd, xn3 = (v[i].w - mean) * rstd;
    float xq0 = xn0 * qw.x + qb4.x, xq1 = xn1 * qw.y + qb4.y;
    float xq2 = xn2 * qw.z + qb4.z, xq3 = xn3 * qw.w + qb4.w;
    float xk0 = xn0 * kw.x + kb4.x, xk1 = xn1 * kw.y + kb4.y;
    float xk2 = xn2 * kw.z + kb4.z, xk3 = xn3 * kw.w + kb4.w;
    float k0 = xk0 * sigm(kp.x), k1 = xk1 * sigm(kp.y);
    float k2 = xk2 * sigm(kp.z), k3 = xk3 * sigm(kp.w);
    ksq += k0 * k0 + k1 * k1 + k2 * k2 + k3 * k3;
    ((ushort4*)xqn_bf)[o4 + idx] = make_ushort4(f2bf(xq0), f2bf(xq1), f2bf(xq2), f2bf(xq3));
    ((ushort4*)kr)[o4 + idx] = make_ushort4(f2bf(k0), f2bf(k1), f2bf(k2), f2bf(k3));
  }
  for (int off = 32; off; off >>= 1) ksq += __shfl_xor(ksq, off);
  if (lane == 0) krowsq[row] = ksq;   // contention-free per-row store
}

// ---------------- qr GEMM: qr = (xqn @ qW^T + qb) * sig(q_prime); + norms --
// grid 1024: c=lid>>7 (8 col-tiles), r=lid&127 -> XCD=r&7 (A-panel reuse).
__global__ __launch_bounds__(256, 3) void qr_gemm_kernel(
    const uint16_t* __restrict__ xqn_bf, const uint16_t* __restrict__ qWbf,
    const float* __restrict__ qb, const float* __restrict__ q_prime,
    uint16_t* __restrict__ qr, float* __restrict__ qnormsq)
{
  __shared__ uint16_t sA[3 * SLOT128], sB[3 * SLOT128];
  const int lid = blockIdx.x;
  const int c = lid >> 7, r = lid & 127;
  f32x4 acc[4][4];
#pragma unroll
  for (int i = 0; i < 4; i++)
#pragma unroll
    for (int j = 0; j < 4; j++) acc[i][j] = (f32x4)0.0f;

  gemm128(xqn_bf + (size_t)r * 128 * 1024, 1024,
          qWbf + (size_t)c * 128 * 1024, 1024, 1024, sA, sB, acc);

  const int tid = threadIdx.x, lane = tid & 63, w = tid >> 6;
  const int m16 = lane & 15, quad = lane >> 4;
  const int rbase = r * 128 + (w >> 1) * 64, cbase = c * 128 + (w & 1) * 64;
#pragma unroll
  for (int mi = 0; mi < 4; mi++) {
    const int gr0 = rbase + mi * 16 + quad * 4;
    float rsq[4] = {0.f, 0.f, 0.f, 0.f};
#pragma unroll
    for (int ni = 0; ni < 4; ni++) {
      const int gc = cbase + ni * 16 + m16;
      const float scale = sigm(q_prime[gc]);
      const float bias = qb[gc];
#pragma unroll
      for (int rr = 0; rr < 4; rr++) {
        float val = (acc[mi][ni][rr] + bias) * scale;
        qr[(size_t)(gr0 + rr) * 1024 + gc] = f2bf(val);
        rsq[rr] += val * val;
      }
    }
#pragma unroll
    for (int rr = 0; rr < 4; rr++) {
      float tq = rsq[rr];
      tq += __shfl_xor(tq, 1); tq += __shfl_xor(tq, 2);
      tq += __shfl_xor(tq, 4); tq += __shfl_xor(tq, 8);
      if (m16 == 0) atomicAdd(&qnormsq[gr0 + rr], tq);
    }
  }
}

// ---------------- bound: Mhat[b] = max||qr|| * max||kr|| / 32 -------------
__global__ void bound_kernel(const float* __restrict__ qnormsq,
                             const float* __restrict__ krowsq, float* __restrict__ MZ)
{
  const int b = blockIdx.x, tid = threadIdx.x, lane = tid & 63, w = tid >> 6;
  float mq = 0.f, mk = 0.f;
  for (int i = tid; i < 2048; i += 256) {
    mq = fmaxf(mq, qnormsq[b * 2048 + i]);
    mk = fmaxf(mk, krowsq[b * 2048 + i]);
  }
  for (int off = 32; off; off >>= 1) {
    mq = fmaxf(mq, __shfl_xor(mq, off));
    mk = fmaxf(mk, __shfl_xor(mk, off));
  }
  __shared__ float rm[4], rk[4];
  if (lane == 0) { rm[w] = mq; rk[w] = mk; }
  __syncthreads();
  if (tid == 0) {
    float qmax = fmaxf(fmaxf(rm[0], rm[1]), fmaxf(rm[2], rm[3]));
    float kmax = fmaxf(fmaxf(rk[0], rk[1]), fmaxf(rk[2], rk[3]));
    MZ[b] = sqrtf(qmax * kmax) * 0.03125f;   // rigorous: s <= ||q||*||k||/32
  }
}

// ---- transpose+scale: vrt[b,h,t] = kr[b,t,h] * gate2[h] (vr eliminated) --
__global__ void transpose_kernel(const uint16_t* __restrict__ kr,
                                 const float* __restrict__ gate2,
                                 uint16_t* __restrict__ vrt)
{
  __shared__ uint16_t t[64 * 72];
  const int b = blockIdx.z;
  const int t0 = blockIdx.x * 64, h0 = blockIdx.y * 64;
  const uint16_t* src = kr + (size_t)b * 2048 * 1024;
#pragma unroll
  for (int p = 0; p < 2; p++) {
    int flat = p * 256 + threadIdx.x;
    int r = flat >> 3, c = (flat & 7) * 8;
    *(uint4*)(&t[r * 72 + c]) = *(const uint4*)(src + (size_t)(t0 + r) * 1024 + h0 + c);
  }
  __syncthreads();
  uint16_t* dst = vrt + (size_t)b * 1024 * 2048;
#pragma unroll
  for (int p = 0; p < 2; p++) {
    int flat = p * 256 + threadIdx.x;
    int oh = flat >> 3, oc = (flat & 7) * 8;
    const float g = gate2[h0 + oh];
    union { uint16_t e[8]; uint4 v; } u;
#pragma unroll
    for (int j = 0; j < 8; j++) u.e[j] = f2bf(bf2f(t[(oc + j) * 72 + oh]) * g);
    *(uint4*)(dst + (size_t)(h0 + oh) * 2048 + t0 + oc) = u.v;
  }
}

// ---------------- scores GEMM: P' = exp(s - Mhat), partial Z --------------
// grid 2048: b=lid>>8, c=(lid>>4)&15, r=lid&15 -> XCD=r&7 (A-panel reuse).
__global__ __launch_bounds__(256, 3) void scores_kernel(
    const uint16_t* __restrict__ qr, const uint16_t* __restrict__ kr,
    const float* __restrict__ MZ,
    uint16_t* __restrict__ scores, float* __restrict__ blockZ)
{
  __shared__ uint16_t sA[3 * SLOT128], sB[3 * SLOT128];
  __shared__ float redz[4];
  const int lid = blockIdx.x;
  const int b = lid >> 8, c = (lid >> 4) & 15, r = lid & 15;
  f32x4 acc[4][4];
#pragma unroll
  for (int i = 0; i < 4; i++)
#pragma unroll
    for (int j = 0; j < 4; j++) acc[i][j] = (f32x4)0.0f;

  gemm128(qr + (size_t)b * 2048 * 1024 + (size_t)r * 128 * 1024, 1024,
          kr + (size_t)b * 2048 * 1024 + (size_t)c * 128 * 1024, 1024,
          1024, sA, sB, acc);

  const float Mhat = MZ[b];
  const int tid = threadIdx.x, lane = tid & 63, w = tid >> 6;
  const int m16 = lane & 15, quad = lane >> 4;
  const int rbase = r * 128 + (w >> 1) * 64, cbase = c * 128 + (w & 1) * 64;
  uint16_t* S = scores + ((size_t)b << 22);
  float zt = 0.f;
#pragma unroll
  for (int mi = 0; mi < 4; mi++) {
    const int gr0 = rbase + mi * 16 + quad * 4;
#pragma unroll
    for (int ni = 0; ni < 4; ni++) {
      const int gc = cbase + ni * 16 + m16;
#pragma unroll
      for (int rr = 0; rr < 4; rr++) {
        float pe = __expf(acc[mi][ni][rr] * 0.03125f - Mhat);
        zt += pe;
        S[(size_t)(gr0 + rr) * 2048 + gc] = f2bf(pe);
      }
    }
  }
  for (int off = 32; off; off >>= 1) zt += __shfl_xor(zt, off);
  if (lane == 0) redz[w] = zt;
  __syncthreads();
  if (tid == 0) blockZ[lid] = redz[0] + redz[1] + redz[2] + redz[3];
}

// ---------------- Z reduce: per-batch sum of 256 block Z ------------------
__global__ void zreduce_kernel(const float* __restrict__ blockZ, float* __restrict__ MZ)
{
  const int b = blockIdx.x, tid = threadIdx.x, lane = tid & 63, w = tid >> 6;
  float z = blockZ[b * 256 + tid];
  for (int off = 32; off; off >>= 1) z += __shfl_xor(z, off);
  __shared__ float rz[4];
  if (lane == 0) rz[w] = z;
  __syncthreads();
  if (tid == 0) MZ[8 + b] = rz[0] + rz[1] + rz[2] + rz[3];
}

// ---------------- PV GEMM: out = P' @ vrt^T / Z + xqn (bf16 residual) -----
// grid 1024: b=lid>>7, c=(lid>>4)&7, r=lid&15 -> XCD=r&7 (P-panel reuse).
__global__ __launch_bounds__(256, 3) void pv_gemm_kernel(
    const uint16_t* __restrict__ P, const uint16_t* __restrict__ vrt,
    const float* __restrict__ MZ, const uint16_t* __restrict__ xqn_bf,
    float* __restrict__ out)
{
  __shared__ uint16_t sA[3 * SLOT128], sB[3 * SLOT128];
  const int lid = blockIdx.x;
  const int b = lid >> 7, c = (lid >> 4) & 7, r = lid & 15;
  f32x4 acc[4][4];
#pragma unroll
  for (int i = 0; i < 4; i++)
#pragma unroll
    for (int j = 0; j < 4; j++) acc[i][j] = (f32x4)0.0f;

  gemm128(P + ((size_t)b << 22) + (size_t)r * 128 * 2048, 2048,
          vrt + (size_t)b * 1024 * 2048 + (size_t)c * 128 * 2048, 2048,
          2048, sA, sB, acc);

  const float invZ = 1.0f / MZ[8 + b];
  const int tid = threadIdx.x, lane = tid & 63, w = tid >> 6;
  const int m16 = lane & 15, quad = lane >> 4;
  const int rbase = r * 128 + (w >> 1) * 64, cbase = c * 128 + (w & 1) * 64;
#pragma unroll
  for (int mi = 0; mi < 4; mi++) {
    const int gr0 = rbase + mi * 16 + quad * 4;
#pragma unroll
    for (int ni = 0; ni < 4; ni++) {
      const int gc = cbase + ni * 16 + m16;
#pragma unroll
      for (int rr = 0; rr < 4; rr++) {
        size_t o = ((size_t)b * 2048 + gr0 + rr) * 1024 + gc;
        out[o] = acc[mi][ni][rr] * invZ + bf2f(xqn_bf[o]);
      }
    }
  }
}

extern "C" void kernel_launch(void* const* d_in, const int* in_sizes, int n_in,
                              void* d_out, int out_size, void* d_ws, size_t ws_size,
                              hipStream_t stream) {
  const float* x       = (const float*)d_in[0];
  const float* qn_w    = (const float*)d_in[1];
  const float* qn_b    = (const float*)d_in[2];
  const float* kvn_w   = (const float*)d_in[3];
  const float* kvn_b   = (const float*)d_in[4];
  const float* q_prime = (const float*)d_in[5];
  const float* k_prime = (const float*)d_in[6];
  const float* v_prime = (const float*)d_in[7];
  const float* qW      = (const float*)d_in[8];
  const float* qb      = (const float*)d_in[9];
  const float* v1W     = (const float*)d_in[10];
  const float* v1b     = (const float*)d_in[11];
  const float* v2W     = (const float*)d_in[12];
  const float* v2b     = (const float*)d_in[13];
  float* out = (float*)d_out;

  const size_t BS = 16384, H = 1024;
  char* ws = (char*)d_ws;
  size_t off = 0;
  auto alloc = [&](size_t bytes) -> char* {
    char* p = ws + off;
    off = (off + bytes + 255) & ~(size_t)255;
    return p;
  };
  float*    gate2   = (float*)alloc(H * 4);
  float*    MZ      = (float*)alloc(16 * 4);        // [0..7]=Mhat, [8..15]=Z
  float*    blockZ  = (float*)alloc(2048 * 4);
  float*    qnormsq = (float*)alloc(16384 * 4);     // atomicAdd target (memset)
  float*    krowsq  = (float*)alloc(16384 * 4);     // plain per-row stores
  uint16_t* qWbf    = (uint16_t*)alloc(H * H * 2);
  uint16_t* xqn_bf  = (uint16_t*)alloc(BS * H * 2); // lives to the end
  uint16_t* kr      = (uint16_t*)alloc(BS * H * 2);
  uint16_t* scores  = (uint16_t*)alloc(BS * H * 2 * 2);  // 64 MB
  uint16_t* vrt     = (uint16_t*)alloc(BS * H * 2);
  uint16_t* qr      = (uint16_t*)alloc(BS * H * 2);

  hipMemsetAsync(qnormsq, 0, 16384 * 4, stream);
  gate_kernel<<<256, 256, 0, stream>>>(v_prime, v1W, v1b, v2W, v2b, k_prime, gate2);
  cvt_kernel<<<1024, 256, 0, stream>>>(qW, qWbf);
  ln_kernel<<<4096, 256, 0, stream>>>(x, qn_w, qn_b, kvn_w, kvn_b, k_prime,
                                      xqn_bf, kr, krowsq);
  qr_gemm_kernel<<<1024, 256, 0, stream>>>(xqn_bf, qWbf, qb, q_prime, qr, qnormsq);
  transpose_kernel<<<dim3(32, 16, 8), 256, 0, stream>>>(kr, gate2, vrt);
  bound_kernel<<<8, 256, 0, stream>>>(qnormsq, krowsq, MZ);
  scores_kernel<<<2048, 256, 0, stream>>>(qr, kr, MZ, scores, blockZ);
  zreduce_kernel<<<8, 256, 0, stream>>>(blockZ, MZ);
  pv_gemm_kernel<<<1024, 256, 0, stream>>>(scores, vrt, MZ, xqn_bf, out);
}

// Round 7
// 358.278 us; speedup vs baseline: 1.1067x; 1.1067x over previous
//
#include <hip/hip_runtime.h>
#include <stdint.h>

// attention_block: B=8, S=2048, H=1024, fp32 in/out, bf16 internal GEMMs.
// R11: consolidation. GEMM core reverted to R7 exactly (best measured:
// 367.5us; R8/R9/R10 schedule variants all >= 370). Dispatch count 10 -> 6:
//  - qnormsq memset folded into ln (blocks 0..63);
//  - gate + cvt merged (blockIdx branch);
//  - bound_kernel gone: scores blocks compute Mhat in a prologue (fmax is
//    exact -> identical value in every block);
//  - zreduce gone: pv blocks reduce their batch's 64 blockZ in fixed order.
// Launch chain: gatecvt -> ln -> qr -> transpose -> scores -> pv.

#define DEVI __device__ __forceinline__

typedef __bf16 bf16x8 __attribute__((ext_vector_type(8)));
typedef float  f32x4  __attribute__((ext_vector_type(4)));

typedef __attribute__((address_space(3))) uint32_t lds_u32_t;
typedef __attribute__((address_space(1))) uint32_t glb_u32_t;

DEVI uint16_t f2bf(float f) {
  union { float f; uint32_t u; } v; v.f = f;
  uint32_t r = (v.u + 0x7fffu + ((v.u >> 16) & 1u)) >> 16;  // RNE
  return (uint16_t)r;
}
DEVI float bf2f(uint16_t b) {
  union { uint32_t u; float f; } v; v.u = ((uint32_t)b) << 16;
  return v.f;
}
DEVI float sigm(float x) { return 1.0f / (1.0f + __expf(-x)); }

DEVI void gl_lds16(const void* g, const void* lds_base) {
  __builtin_amdgcn_global_load_lds((glb_u32_t*)(uintptr_t)g,
                                   (lds_u32_t*)(uint32_t)(uintptr_t)lds_base,
                                   16, 0, 0);
}

// ================= 256x256 GEMM core (R7, NT layout) =======================
// C[256x256] += A[256xK] * B[256xK]^T. 512 threads = 8 waves (2M x 4N),
// per-wave C tile 128x64 -> acc[8][4]. K consumed in 64-wide tiles staged as
// 32-wide HALVES (256x32 bf16 = 16 KB). Ring of 4 half-slots per operand
// (128 KB LDS). Half h in slot h&3; tile t consumes halves 2t (ks=0) and
// 2t+1 (ks=1), staging halves 2t+3 (B@p0, A@p1) and 2t+4 (B@p2, A@p3).
// Per phase: {ds_read frags, stage_half, [vmcnt @p3], s_barrier, MFMA x16}.
// bv (B frags) read once per ks, reused for both A-row-half phases.
// Chunk XOR ((row>>1)&3) both sides -> conflict-free b128 (verified 0 cnf).

#define SLOT (256 * 32)

DEVI void stage_half(const uint16_t* __restrict__ src, size_t ld, int kbase,
                     uint16_t* slot, int tid) {
#pragma unroll
  for (int q = 0; q < 2; q++) {
    const int idx = q * 512 + tid;                    // 0..1023 : 16B chunk id
    const int r = idx >> 2;                           // row 0..255
    const int cl = (((idx & 3) ^ ((r >> 1) & 3)) * 8); // swizzled source col
    gl_lds16(src + (size_t)r * ld + (kbase + cl),
             slot + (size_t)(q * 512 + (tid & ~63)) * 8);  // wave-uniform base
  }
}

DEVI void gemm256(const uint16_t* __restrict__ A, size_t lda,
                  const uint16_t* __restrict__ B, size_t ldb,
                  int K, uint16_t* sA, uint16_t* sB, f32x4 (&acc)[8][4])
{
  const int tid = threadIdx.x, lane = tid & 63, w = tid >> 6;
  const int wr = (w >> 2) * 128, wc = (w & 3) * 64;
  const int m16 = lane & 15, quad = lane >> 4;
  const int NT = K >> 6, NH = K >> 5;

  // prologue: halves 0,1 landed; half 2 left in flight (4 loads)
  stage_half(B, ldb, 0, sB, tid);
  stage_half(A, lda, 0, sA, tid);
  stage_half(B, ldb, 32, sB + SLOT, tid);
  stage_half(A, lda, 32, sA + SLOT, tid);
  stage_half(B, ldb, 64, sB + 2 * SLOT, tid);
  stage_half(A, lda, 64, sA + 2 * SLOT, tid);
  asm volatile("s_waitcnt vmcnt(4)" ::: "memory");
  __builtin_amdgcn_s_barrier();

  const int sw = (quad ^ ((m16 >> 1) & 3)) * 8;       // conflict-free chunk

  for (int t = 0; t < NT; t++) {
#pragma unroll
    for (int ks = 0; ks < 2; ks++) {
      const uint16_t* a_s = sA + ((2 * t + ks) & 3) * SLOT;
      const uint16_t* b_s = sB + ((2 * t + ks) & 3) * SLOT;
      const int h = 2 * t + 3 + ks;

      // ---- phase A (g=0): read bv + af(g0); stage B-half(h) ----
      bf16x8 bv[4], af[4];
#pragma unroll
      for (int i = 0; i < 4; i++)
        bv[i] = *(const bf16x8*)(b_s + (wc + i * 16 + m16) * 32 + sw);
#pragma unroll
      for (int i = 0; i < 4; i++)
        af[i] = *(const bf16x8*)(a_s + (wr + i * 16 + m16) * 32 + sw);
      if (h < NH) stage_half(B, ldb, h * 32, sB + (h & 3) * SLOT, tid);
      __builtin_amdgcn_s_barrier();
      __builtin_amdgcn_s_setprio(1);
#pragma unroll
      for (int mi = 0; mi < 4; mi++)
#pragma unroll
        for (int ni = 0; ni < 4; ni++)
          acc[mi][ni] = __builtin_amdgcn_mfma_f32_16x16x32_bf16(
              af[mi], bv[ni], acc[mi][ni], 0, 0, 0);
      __builtin_amdgcn_s_setprio(0);

      // ---- phase B (g=1): read af(g1); stage A-half(h); vmcnt @ks==1 ----
      bf16x8 af2[4];
#pragma unroll
      for (int i = 0; i < 4; i++)
        af2[i] = *(const bf16x8*)(a_s + (wr + 64 + i * 16 + m16) * 32 + sw);
      if (h < NH) stage_half(A, lda, h * 32, sA + (h & 3) * SLOT, tid);
      if (ks == 1) {
        if (t < NT - 2) asm volatile("s_waitcnt vmcnt(4)" ::: "memory");
        else            asm volatile("s_waitcnt vmcnt(0)" ::: "memory");
      }
      __builtin_amdgcn_s_barrier();
      __builtin_amdgcn_s_setprio(1);
#pragma unroll
      for (int mi = 0; mi < 4; mi++)
#pragma unroll
        for (int ni = 0; ni < 4; ni++)
          acc[4 + mi][ni] = __builtin_amdgcn_mfma_f32_16x16x32_bf16(
              af2[mi], bv[ni], acc[4 + mi][ni], 0, 0, 0);
      __builtin_amdgcn_s_setprio(0);
    }
  }
}

// ------- fused gate + cvt: bid<1024 -> qW cvt; bid>=1024 -> gate ----------
__global__ void gatecvt_kernel(const float* __restrict__ qW, uint16_t* __restrict__ qWbf,
                               const float* __restrict__ v_prime,
                               const float* __restrict__ v1W, const float* __restrict__ v1b,
                               const float* __restrict__ v2W, const float* __restrict__ v2b,
                               const float* __restrict__ k_prime,
                               float* __restrict__ gate2)
{
  const int bid = blockIdx.x;
  if (bid < 1024) {
    size_t i = ((size_t)bid * 256 + threadIdx.x) * 4;
    float4 v = *(const float4*)(qW + i);
    *(ushort4*)(qWbf + i) = make_ushort4(f2bf(v.x), f2bf(v.y), f2bf(v.z), f2bf(v.w));
    return;
  }
  const int tid = threadIdx.x, lane = tid & 63, w = tid >> 6;
  const int j = (bid - 1024) * 4 + w;
  float d1 = 0.f, d2 = 0.f;
  for (int it = 0; it < 16; it++) {
    int i = it * 64 + lane;
    float vp = sigm(v_prime[i]);
    d1 += vp * v1W[(size_t)j * 1024 + i];
    d2 += vp * v2W[(size_t)j * 1024 + i];
  }
  for (int off = 32; off; off >>= 1) { d1 += __shfl_xor(d1, off); d2 += __shfl_xor(d2, off); }
  if (lane == 0)
    gate2[j] = sigm(d1 + v1b[j]) * tanhf(d2 + v2b[j]) / sigm(k_prime[j]);
}

// ---------------- LayerNorm: wave-per-row; xqn + kr; zeroes qnormsq -------
__global__ __launch_bounds__(256) void ln_kernel(
    const float* __restrict__ x,
    const float* __restrict__ qn_w, const float* __restrict__ qn_b,
    const float* __restrict__ kvn_w, const float* __restrict__ kvn_b,
    const float* __restrict__ k_prime,
    uint16_t* __restrict__ xqn_bf, uint16_t* __restrict__ kr,
    float* __restrict__ krowsq, float* __restrict__ qnormsq)
{
  if (blockIdx.x < 64) qnormsq[blockIdx.x * 256 + threadIdx.x] = 0.f;

  const int lane = threadIdx.x & 63, w = threadIdx.x >> 6;
  const int row = blockIdx.x * 4 + w;
  const float4* xr = (const float4*)(x + (size_t)row * 1024);
  float4 v[4];
  float s = 0.f, sq = 0.f;
#pragma unroll
  for (int i = 0; i < 4; i++) {
    v[i] = xr[i * 64 + lane];
    s  += v[i].x + v[i].y + v[i].z + v[i].w;
    sq += v[i].x * v[i].x + v[i].y * v[i].y + v[i].z * v[i].z + v[i].w * v[i].w;
  }
  for (int off = 32; off; off >>= 1) { s += __shfl_xor(s, off); sq += __shfl_xor(sq, off); }
  const float mean = s * (1.f / 1024.f);
  const float rstd = rsqrtf(sq * (1.f / 1024.f) - mean * mean + 1e-5f);

  float ksq = 0.f;
  const size_t o4 = (size_t)row * 256;
#pragma unroll
  for (int i = 0; i < 4; i++) {
    const int idx = i * 64 + lane;
    float4 qw = ((const float4*)qn_w)[idx],  qb4 = ((const float4*)qn_b)[idx];
    float4 kw = ((const float4*)kvn_w)[idx], kb4 = ((const float4*)kvn_b)[idx];
    float4 kp = ((const float4*)k_prime)[idx];
    float xn0 = (v[i].x - mean) * rstd, xn1 = (v[i].y - mean) * rstd;
    float xn2 = (v[i].z - mean) * rstd, xn3 = (v[i].w - mean) * rstd;
    float xq0 = xn0 * qw.x + qb4.x, xq1 = xn1 * qw.y + qb4.y;
    float xq2 = xn2 * qw.z + qb4.z, xq3 = xn3 * qw.w + qb4.w;
    float xk0 = xn0 * kw.x + kb4.x, xk1 = xn1 * kw.y + kb4.y;
    float xk2 = xn2 * kw.z + kb4.z, xk3 = xn3 * kw.w + kb4.w;
    float k0 = xk0 * sigm(kp.x), k1 = xk1 * sigm(kp.y);
    float k2 = xk2 * sigm(kp.z), k3 = xk3 * sigm(kp.w);
    ksq += k0 * k0 + k1 * k1 + k2 * k2 + k3 * k3;
    ((ushort4*)xqn_bf)[o4 + idx] = make_ushort4(f2bf(xq0), f2bf(xq1), f2bf(xq2), f2bf(xq3));
    ((ushort4*)kr)[o4 + idx] = make_ushort4(f2bf(k0), f2bf(k1), f2bf(k2), f2bf(k3));
  }
  for (int off = 32; off; off >>= 1) ksq += __shfl_xor(ksq, off);
  if (lane == 0) krowsq[row] = ksq;   // contention-free per-row store
}

// ---------------- qr GEMM: qr = (xqn @ qW^T + qb) * sig(q_prime); + norms --
__global__ __launch_bounds__(512, 2) void qr_gemm_kernel(
    const uint16_t* __restrict__ xqn_bf, const uint16_t* __restrict__ qWbf,
    const float* __restrict__ qb, const float* __restrict__ q_prime,
    uint16_t* __restrict__ qr, float* __restrict__ qnormsq)
{
  __shared__ uint16_t sA[4 * SLOT], sB[4 * SLOT];
  const int lid = blockIdx.x;
  const int c = lid >> 6, r = lid & 63;     // XCD = r&7 -> A-panel reuse
  f32x4 acc[8][4];
#pragma unroll
  for (int i = 0; i < 8; i++)
#pragma unroll
    for (int j = 0; j < 4; j++) acc[i][j] = (f32x4)0.0f;

  gemm256(xqn_bf + (size_t)r * 256 * 1024, 1024,
          qWbf + (size_t)c * 256 * 1024, 1024, 1024, sA, sB, acc);

  const int tid = threadIdx.x, lane = tid & 63, w = tid >> 6;
  const int m16 = lane & 15, quad = lane >> 4;
  const int rbase = r * 256 + (w >> 2) * 128, cbase = c * 256 + (w & 3) * 64;
#pragma unroll
  for (int ai = 0; ai < 8; ai++) {
    const int gr0 = rbase + (ai >> 2) * 64 + (ai & 3) * 16 + quad * 4;
    float rsq[4] = {0.f, 0.f, 0.f, 0.f};
#pragma unroll
    for (int ni = 0; ni < 4; ni++) {
      const int gc = cbase + ni * 16 + m16;
      const float scale = sigm(q_prime[gc]);
      const float bias = qb[gc];
#pragma unroll
      for (int rr = 0; rr < 4; rr++) {
        float val = (acc[ai][ni][rr] + bias) * scale;
        qr[(size_t)(gr0 + rr) * 1024 + gc] = f2bf(val);
        rsq[rr] += val * val;
      }
    }
#pragma unroll
    for (int rr = 0; rr < 4; rr++) {
      float tq = rsq[rr];
      tq += __shfl_xor(tq, 1); tq += __shfl_xor(tq, 2);
      tq += __shfl_xor(tq, 4); tq += __shfl_xor(tq, 8);
      if (m16 == 0) atomicAdd(&qnormsq[gr0 + rr], tq);
    }
  }
}

// ---- transpose+scale: vrt[b,h,t] = kr[b,t,h] * gate2[h] (vr eliminated) --
__global__ void transpose_kernel(const uint16_t* __restrict__ kr,
                                 const float* __restrict__ gate2,
                                 uint16_t* __restrict__ vrt)
{
  __shared__ uint16_t t[64 * 72];
  const int b = blockIdx.z;
  const int t0 = blockIdx.x * 64, h0 = blockIdx.y * 64;
  const uint16_t* src = kr + (size_t)b * 2048 * 1024;
#pragma unroll
  for (int p = 0; p < 2; p++) {
    int flat = p * 256 + threadIdx.x;
    int r = flat >> 3, c = (flat & 7) * 8;
    *(uint4*)(&t[r * 72 + c]) = *(const uint4*)(src + (size_t)(t0 + r) * 1024 + h0 + c);
  }
  __syncthreads();
  uint16_t* dst = vrt + (size_t)b * 1024 * 2048;
#pragma unroll
  for (int p = 0; p < 2; p++) {
    int flat = p * 256 + threadIdx.x;
    int oh = flat >> 3, oc = (flat & 7) * 8;
    const float g = gate2[h0 + oh];
    union { uint16_t e[8]; uint4 v; } u;
#pragma unroll
    for (int j = 0; j < 8; j++) u.e[j] = f2bf(bf2f(t[(oc + j) * 72 + oh]) * g);
    *(uint4*)(dst + (size_t)(h0 + oh) * 2048 + t0 + oc) = u.v;
  }
}

// ---------------- scores GEMM: P' = exp(s - Mhat), partial Z --------------
// grid 512: b=lid>>6, c=(lid>>3)&7, r=lid&7 -> XCD=r (A-panel L2 reuse).
// Mhat computed per-block in prologue (fmax exact -> identical everywhere).
__global__ __launch_bounds__(512, 2) void scores_kernel(
    const uint16_t* __restrict__ qr, const uint16_t* __restrict__ kr,
    const float* __restrict__ qnormsq, const float* __restrict__ krowsq,
    uint16_t* __restrict__ scores, float* __restrict__ blockZ)
{
  __shared__ uint16_t sA[4 * SLOT], sB[4 * SLOT];
  __shared__ float redz[8], rm[8], rk[8], sMhat;
  const int lid = blockIdx.x;
  const int b = lid >> 6, c = (lid >> 3) & 7, r = lid & 7;
  const int tid = threadIdx.x, lane = tid & 63, w = tid >> 6;

  // prologue: Mhat[b] = sqrt(max||qr||^2 * max||kr||^2)/32
  {
    float mq = 0.f, mk = 0.f;
    for (int i = tid; i < 2048; i += 512) {
      mq = fmaxf(mq, qnormsq[b * 2048 + i]);
      mk = fmaxf(mk, krowsq[b * 2048 + i]);
    }
    for (int off = 32; off; off >>= 1) {
      mq = fmaxf(mq, __shfl_xor(mq, off));
      mk = fmaxf(mk, __shfl_xor(mk, off));
    }
    if (lane == 0) { rm[w] = mq; rk[w] = mk; }
    __syncthreads();
    if (tid == 0) {
      float qmax = rm[0], kmax = rk[0];
#pragma unroll
      for (int i = 1; i < 8; i++) { qmax = fmaxf(qmax, rm[i]); kmax = fmaxf(kmax, rk[i]); }
      sMhat = sqrtf(qmax * kmax) * 0.03125f;
    }
  }

  f32x4 acc[8][4];
#pragma unroll
  for (int i = 0; i < 8; i++)
#pragma unroll
    for (int j = 0; j < 4; j++) acc[i][j] = (f32x4)0.0f;

  gemm256(qr + (size_t)b * 2048 * 1024 + (size_t)r * 256 * 1024, 1024,
          kr + (size_t)b * 2048 * 1024 + (size_t)c * 256 * 1024, 1024,
          1024, sA, sB, acc);

  const float Mhat = sMhat;   // visible: written before gemm's barriers
  const int m16 = lane & 15, quad = lane >> 4;
  const int rbase = r * 256 + (w >> 2) * 128, cbase = c * 256 + (w & 3) * 64;
  uint16_t* S = scores + ((size_t)b << 22);
  float zt = 0.f;
#pragma unroll
  for (int ai = 0; ai < 8; ai++) {
    const int gr0 = rbase + (ai >> 2) * 64 + (ai & 3) * 16 + quad * 4;
#pragma unroll
    for (int ni = 0; ni < 4; ni++) {
      const int gc = cbase + ni * 16 + m16;
#pragma unroll
      for (int rr = 0; rr < 4; rr++) {
        float pe = __expf(acc[ai][ni][rr] * 0.03125f - Mhat);
        zt += pe;
        S[(size_t)(gr0 + rr) * 2048 + gc] = f2bf(pe);
      }
    }
  }
  for (int off = 32; off; off >>= 1) zt += __shfl_xor(zt, off);
  if (lane == 0) redz[w] = zt;
  __syncthreads();
  if (tid == 0) {
    float sz = 0.f;
#pragma unroll
    for (int i = 0; i < 8; i++) sz += redz[i];
    blockZ[lid] = sz;
  }
}

// ---------------- PV GEMM: out = P' @ vrt^T / Z + xqn (bf16 residual) -----
// grid 256: b=lid>>5, c=(lid>>3)&3, r=lid&7 -> XCD=r (P row-panel reuse).
// Z reduced per-block in prologue (fixed order -> identical within batch).
__global__ __launch_bounds__(512, 2) void pv_gemm_kernel(
    const uint16_t* __restrict__ P, const uint16_t* __restrict__ vrt,
    const float* __restrict__ blockZ, const uint16_t* __restrict__ xqn_bf,
    float* __restrict__ out)
{
  __shared__ uint16_t sA[4 * SLOT], sB[4 * SLOT];
  __shared__ float sZ;
  const int lid = blockIdx.x;
  const int b = lid >> 5, c = (lid >> 3) & 3, r = lid & 7;
  const int tid = threadIdx.x;

  if (tid < 64) {                       // wave 0: fixed-order Z reduce
    float z = blockZ[b * 64 + tid];
    for (int off = 32; off; off >>= 1) z += __shfl_xor(z, off);
    if (tid == 0) sZ = z;
  }

  f32x4 acc[8][4];
#pragma unroll
  for (int i = 0; i < 8; i++)
#pragma unroll
    for (int j = 0; j < 4; j++) acc[i][j] = (f32x4)0.0f;

  gemm256(P + ((size_t)b << 22) + (size_t)r * 256 * 2048, 2048,
          vrt + (size_t)b * 1024 * 2048 + (size_t)c * 256 * 2048, 2048,
          2048, sA, sB, acc);

  const float invZ = 1.0f / sZ;         // visible: written before gemm barriers
  const int lane = tid & 63, w = tid >> 6;
  const int m16 = lane & 15, quad = lane >> 4;
  const int rbase = r * 256 + (w >> 2) * 128, cbase = c * 256 + (w & 3) * 64;
#pragma unroll
  for (int ai = 0; ai < 8; ai++) {
    const int gr0 = rbase + (ai >> 2) * 64 + (ai & 3) * 16 + quad * 4;
#pragma unroll
    for (int ni = 0; ni < 4; ni++) {
      const int gc = cbase + ni * 16 + m16;
#pragma unroll
      for (int rr = 0; rr < 4; rr++) {
        size_t o = ((size_t)b * 2048 + gr0 + rr) * 1024 + gc;
        out[o] = acc[ai][ni][rr] * invZ + bf2f(xqn_bf[o]);
      }
    }
  }
}

extern "C" void kernel_launch(void* const* d_in, const int* in_sizes, int n_in,
                              void* d_out, int out_size, void* d_ws, size_t ws_size,
                              hipStream_t stream) {
  const float* x       = (const float*)d_in[0];
  const float* qn_w    = (const float*)d_in[1];
  const float* qn_b    = (const float*)d_in[2];
  const float* kvn_w   = (const float*)d_in[3];
  const float* kvn_b   = (const float*)d_in[4];
  const float* q_prime = (const float*)d_in[5];
  const float* k_prime = (const float*)d_in[6];
  const float* v_prime = (const float*)d_in[7];
  const float* qW      = (const float*)d_in[8];
  const float* qb      = (const float*)d_in[9];
  const float* v1W     = (const float*)d_in[10];
  const float* v1b     = (const float*)d_in[11];
  const float* v2W     = (const float*)d_in[12];
  const float* v2b     = (const float*)d_in[13];
  float* out = (float*)d_out;

  const size_t BS = 16384, H = 1024;
  char* ws = (char*)d_ws;
  size_t off = 0;
  auto alloc = [&](size_t bytes) -> char* {
    char* p = ws + off;
    off = (off + bytes + 255) & ~(size_t)255;
    return p;
  };
  float*    gate2   = (float*)alloc(H * 4);
  float*    blockZ  = (float*)alloc(2048 * 4);
  float*    qnormsq = (float*)alloc(16384 * 4);     // zeroed by ln blocks 0..63
  float*    krowsq  = (float*)alloc(16384 * 4);     // plain per-row stores
  uint16_t* qWbf    = (uint16_t*)alloc(H * H * 2);
  uint16_t* xqn_bf  = (uint16_t*)alloc(BS * H * 2); // lives to the end
  uint16_t* kr      = (uint16_t*)alloc(BS * H * 2);
  uint16_t* scores  = (uint16_t*)alloc(BS * H * 2 * 2);  // 64 MB
  uint16_t* vrt     = (uint16_t*)alloc(BS * H * 2);
  uint16_t* qr      = (uint16_t*)alloc(BS * H * 2);

  gatecvt_kernel<<<1280, 256, 0, stream>>>(qW, qWbf, v_prime, v1W, v1b, v2W, v2b,
                                           k_prime, gate2);
  ln_kernel<<<4096, 256, 0, stream>>>(x, qn_w, qn_b, kvn_w, kvn_b, k_prime,
                                      xqn_bf, kr, krowsq, qnormsq);
  qr_gemm_kernel<<<256, 512, 0, stream>>>(xqn_bf, qWbf, qb, q_prime, qr, qnormsq);
  transpose_kernel<<<dim3(32, 16, 8), 256, 0, stream>>>(kr, gate2, vrt);
  scores_kernel<<<512, 512, 0, stream>>>(qr, kr, qnormsq, krowsq, scores, blockZ);
  pv_gemm_kernel<<<256, 512, 0, stream>>>(scores, vrt, blockZ, xqn_bf, out);
}